// Round 1
// baseline (158.277 us; speedup 1.0000x reference)
//
#include <hip/hip_runtime.h>
#include <hip/hip_bf16.h>

#define DDIM 256
#define NROWS 8192

typedef __attribute__((ext_vector_type(8))) __bf16 bf16x8;
typedef __attribute__((ext_vector_type(4))) float floatx4;

// async global->LDS, 16B per lane. LDS dest is wave-uniform base + lane*16.
__device__ __forceinline__ void async16(const void* g, void* l) {
    __builtin_amdgcn_global_load_lds(
        (const __attribute__((address_space(1))) unsigned int*)g,
        (__attribute__((address_space(3))) unsigned int*)l,
        16, 0, 0);
}

// Kernel 1: L2-normalize rows of U and P to bf16, compute pos_sim (normalized
// dot, un-scaled by 1/T), zero the rowsum accumulator. One wave per row.
__global__ __launch_bounds__(256) void normalize_kernel(
    const float* __restrict__ U, const float* __restrict__ P,
    unsigned short* __restrict__ Un, unsigned short* __restrict__ Pn,
    float* __restrict__ possim, float* __restrict__ rowsum)
{
    const int lane = threadIdx.x & 63;
    const int row  = blockIdx.x * 4 + (threadIdx.x >> 6);
    const size_t base = (size_t)row * DDIM + lane * 4;
    const float4 u4 = *(const float4*)(U + base);
    const float4 p4 = *(const float4*)(P + base);
    float su = u4.x*u4.x + u4.y*u4.y + u4.z*u4.z + u4.w*u4.w;
    float sp = p4.x*p4.x + p4.y*p4.y + p4.z*p4.z + p4.w*p4.w;
    float up = u4.x*p4.x + u4.y*p4.y + u4.z*p4.z + u4.w*p4.w;
    #pragma unroll
    for (int d = 1; d < 64; d <<= 1) {
        su += __shfl_xor(su, d);
        sp += __shfl_xor(sp, d);
        up += __shfl_xor(up, d);
    }
    const float iu = rsqrtf(fmaxf(su, 1e-24f));   // norm >> eps for these inputs
    const float ip = rsqrtf(fmaxf(sp, 1e-24f));
    if (lane == 0) {
        possim[row] = up * iu * ip;
        rowsum[row] = 0.0f;
    }
    union { ushort4 s4; __hip_bfloat16 h[4]; } cu, cp;
    cu.h[0] = __float2bfloat16(u4.x * iu); cu.h[1] = __float2bfloat16(u4.y * iu);
    cu.h[2] = __float2bfloat16(u4.z * iu); cu.h[3] = __float2bfloat16(u4.w * iu);
    cp.h[0] = __float2bfloat16(p4.x * ip); cp.h[1] = __float2bfloat16(p4.y * ip);
    cp.h[2] = __float2bfloat16(p4.z * ip); cp.h[3] = __float2bfloat16(p4.w * ip);
    *(ushort4*)(Un + base) = cu.s4;
    *(ushort4*)(Pn + base) = cp.s4;
}

// Kernel 2: one 128x128 tile of sim = Un * Pn^T per block, K=256 in 4 chunks
// of BK=64. 4 waves in 2x2, each 64x64 via 4x4 MFMA 16x16x32 bf16 tiles.
// LDS layout: [row][granule ^ (row&7)], granule = 8 bf16 (16 B). This keeps
// global_load_lds staging contiguous (HW constraint) AND makes ds_read_b128
// fragment reads 2-way-aliased only (free).
// Epilogue: exp(5*dot), 16-lane shuffle row-reduce, atomicAdd into rowsum.
__global__ __launch_bounds__(256, 3) void sim_exp_rowsum(
    const unsigned short* __restrict__ Un,
    const unsigned short* __restrict__ Pn,
    float* __restrict__ rowsum)
{
    __shared__ __align__(16) unsigned short As[128 * 64];
    __shared__ __align__(16) unsigned short Bs[128 * 64];
    const int tid  = threadIdx.x;
    const int lane = tid & 63;
    const int wv   = tid >> 6;
    const int wr   = wv >> 1, wc = wv & 1;
    const int rowblock = blockIdx.y, colblock = blockIdx.x;

    floatx4 acc[4][4];
    #pragma unroll
    for (int t = 0; t < 4; ++t)
        #pragma unroll
        for (int u = 0; u < 4; ++u)
            acc[t][u] = {0.0f, 0.0f, 0.0f, 0.0f};

    const int srow = lane >> 3;            // row within an 8-row staging group
    const int gg   = (lane & 7) ^ srow;    // swizzled global granule to fetch
    const size_t abase = (size_t)rowblock * 128 * DDIM;
    const size_t bbase = (size_t)colblock * 128 * DDIM;
    const int q = lane >> 4;               // quad
    const int m = lane & 15;

    #pragma unroll
    for (int kc = 0; kc < 4; ++kc) {
        const int k0 = kc * 64;
        __syncthreads();   // all waves done reading previous chunk
        #pragma unroll
        for (int i = 0; i < 4; ++i) {
            const int rg = wv * 4 + i;                 // 8-row group, 0..15
            const int r  = rg * 8 + srow;              // local row 0..127
            async16(Un + abase + (size_t)r * DDIM + k0 + gg * 8, &As[rg * 8 * 64]);
            async16(Pn + bbase + (size_t)r * DDIM + k0 + gg * 8, &Bs[rg * 8 * 64]);
        }
        __syncthreads();   // vmcnt(0) drain + barrier: staging visible
        #pragma unroll
        for (int ks = 0; ks < 2; ++ks) {
            bf16x8 af[4], bfr[4];
            const int gl = ks * 4 + q;                 // logical k-granule 0..7
            const int gp = (gl ^ (m & 7)) * 8;         // swizzled LDS offset
            #pragma unroll
            for (int t = 0; t < 4; ++t) {
                af[t]  = *(const bf16x8*)&As[(wr * 64 + t * 16 + m) * 64 + gp];
                bfr[t] = *(const bf16x8*)&Bs[(wc * 64 + t * 16 + m) * 64 + gp];
            }
            #pragma unroll
            for (int t = 0; t < 4; ++t)
                #pragma unroll
                for (int u = 0; u < 4; ++u)
                    acc[t][u] = __builtin_amdgcn_mfma_f32_16x16x32_bf16(
                        af[t], bfr[u], acc[t][u], 0, 0, 0);
        }
    }

    // Epilogue: C/D layout is col = lane&15, row = (lane>>4)*4 + reg.
    // exp(sim) with 1/T = 5 folded in; sum over this wave's 64 columns,
    // then reduce the 16 column-lanes and atomically add per row.
    #pragma unroll
    for (int t = 0; t < 4; ++t) {
        #pragma unroll
        for (int r = 0; r < 4; ++r) {
            float s = __expf(5.0f * acc[t][0][r]) + __expf(5.0f * acc[t][1][r])
                    + __expf(5.0f * acc[t][2][r]) + __expf(5.0f * acc[t][3][r]);
            s += __shfl_xor(s, 1);
            s += __shfl_xor(s, 2);
            s += __shfl_xor(s, 4);
            s += __shfl_xor(s, 8);
            if (m == 0) {
                const int grow = rowblock * 128 + wr * 64 + t * 16 + q * 4 + r;
                atomicAdd(&rowsum[grow], s);
            }
        }
    }
}

// Kernel 3: loss = mean_i( log(rowsum_i) - 5 * possim_i ). Single block.
__global__ __launch_bounds__(256) void finalize_kernel(
    const float* __restrict__ rowsum, const float* __restrict__ possim,
    float* __restrict__ out)
{
    float acc = 0.0f;
    for (int i = threadIdx.x; i < NROWS; i += 256)
        acc += __logf(rowsum[i]) - 5.0f * possim[i];
    #pragma unroll
    for (int d = 1; d < 64; d <<= 1) acc += __shfl_xor(acc, d);
    __shared__ float wsum[4];
    if ((threadIdx.x & 63) == 0) wsum[threadIdx.x >> 6] = acc;
    __syncthreads();
    if (threadIdx.x == 0)
        out[0] = (wsum[0] + wsum[1] + wsum[2] + wsum[3]) * (1.0f / (float)NROWS);
}

extern "C" void kernel_launch(void* const* d_in, const int* in_sizes, int n_in,
                              void* d_out, int out_size, void* d_ws, size_t ws_size,
                              hipStream_t stream) {
    const float* U = (const float*)d_in[0];
    const float* P = (const float*)d_in[1];
    float* out = (float*)d_out;
    char* ws = (char*)d_ws;
    // ws layout: Un bf16 [8192*256] (4 MB) | Pn bf16 (4 MB) | rowsum f32 (32 KB)
    //            | possim f32 (32 KB). Total ~8.06 MB.
    unsigned short* Un = (unsigned short*)ws;
    unsigned short* Pn = (unsigned short*)(ws + 4194304);
    float* rowsum = (float*)(ws + 8388608);
    float* possim = (float*)(ws + 8388608 + 32768);

    normalize_kernel<<<NROWS / 4, 256, 0, stream>>>(U, P, Un, Pn, possim, rowsum);
    dim3 g2(64, 64);   // x = col tile, y = row tile
    sim_exp_rowsum<<<g2, 256, 0, stream>>>(Un, Pn, rowsum);
    finalize_kernel<<<1, 256, 0, stream>>>(rowsum, possim, out);
}